// Round 5
// baseline (228.469 us; speedup 1.0000x reference)
//
#include <hip/hip_runtime.h>
#include <hip/hip_bf16.h>

#define N_NODES 50000
#define N_EDGES 200000
#define NBATCH  (N_EDGES / 4)     // 4 edges per wave-batch
// IN_C = 32, HID = 32, OUT_C = 16, EDGE_DIM = 8, EPS = 1e-5

typedef float v2f __attribute__((ext_vector_type(2)));

static __device__ inline v2f sp2(float s) { v2f r; r.x = s; r.y = s; return r; }

static __device__ inline v2f fma2(v2f a, v2f b, v2f c) {
#if __has_builtin(__builtin_elementwise_fma)
    return __builtin_elementwise_fma(a, b, c);
#else
    v2f r; r.x = fmaf(a.x, b.x, c.x); r.y = fmaf(a.y, b.y, c.y); return r;
#endif
}

static __device__ inline v2f max2(v2f a, v2f b) {
#if __has_builtin(__builtin_elementwise_max)
    return __builtin_elementwise_max(a, b);
#else
    v2f r; r.x = fmaxf(a.x, b.x); r.y = fmaxf(a.y, b.y); return r;
#endif
}

static __device__ inline float rflf(float v) {
    return __int_as_float(__builtin_amdgcn_readfirstlane(__float_as_int(v)));
}

// ---------------------------------------------------------------------------
// Edge kernel. Weights live in LDS (padded, 2-way-free b64 reads); each wave
// processes 4 edges per batch, streaming weight k-chunks so each LDS read is
// reused by 4 edges. ea -> SGPRs (wave-uniform). 32-lane contiguous atomics.
// Lane = (i4 = lane>>4, oo = lane&15): owns i in [8*i4, 8*i4+8), o-pair 2oo.
// ---------------------------------------------------------------------------
__global__ __launch_bounds__(256, 3) void edge_kernel(
    const float* __restrict__ x, const int* __restrict__ ei,
    const float* __restrict__ ea, const float* __restrict__ nn_w,
    const float* __restrict__ nn_b, float* __restrict__ agg)
{
    // rows = k*32 + i for k=0..7 (nn_w) and k=8 (bias); each row 16 v2f,
    // padded to 17 v2f -> b64 reads are 2-way bank aliased (free).
    __shared__ v2f wlds[288 * 17];

    for (int f = threadIdx.x; f < 9216; f += 256) {
        const int k = f >> 10;          // 0..8 (8 = bias)
        const int rem = f & 1023;
        const int i = rem >> 5, o = rem & 31;
        const float v = (k < 8) ? nn_w[f] : nn_b[rem];
        ((float*)wlds)[((k * 32 + i) * 17 + (o >> 1)) * 2 + (o & 1)] = v;
    }
    __syncthreads();

    const int lane  = threadIdx.x & 63;
    const int oo    = lane & 15;
    const int i4    = lane >> 4;
    const int ib    = i4 * 8;
    const int vbase = i4 * 136 + oo;    // lane part of v2f index (rows*17 + oo)

    const int wid = __builtin_amdgcn_readfirstlane(
        (int)((blockIdx.x * blockDim.x + threadIdx.x) >> 6));
    const int nwv = (gridDim.x * blockDim.x) >> 6;

    int b = wid;
    if (b >= NBATCH) return;

    // prologue: meta loads for first batch
    int4 nsrc = *(const int4*)(ei + 4 * b);
    int4 ndst = *(const int4*)(ei + N_EDGES + 4 * b);
    float4 nea[8];
    {
        const float4* p = (const float4*)(ea + (size_t)b * 32);
#pragma unroll
        for (int q = 0; q < 8; ++q) nea[q] = p[q];
    }

    while (true) {
        // ---- materialize wave-uniform meta into SGPRs ----
        int s[4], d[4];
        s[0] = __builtin_amdgcn_readfirstlane(nsrc.x);
        s[1] = __builtin_amdgcn_readfirstlane(nsrc.y);
        s[2] = __builtin_amdgcn_readfirstlane(nsrc.z);
        s[3] = __builtin_amdgcn_readfirstlane(nsrc.w);
        d[0] = __builtin_amdgcn_readfirstlane(ndst.x);
        d[1] = __builtin_amdgcn_readfirstlane(ndst.y);
        d[2] = __builtin_amdgcn_readfirstlane(ndst.z);
        d[3] = __builtin_amdgcn_readfirstlane(ndst.w);
        float eas[4][8];
#pragma unroll
        for (int q = 0; q < 8; ++q) {
            const int e2 = q >> 1, kb = (q & 1) * 4;
            eas[e2][kb + 0] = rflf(nea[q].x);
            eas[e2][kb + 1] = rflf(nea[q].y);
            eas[e2][kb + 2] = rflf(nea[q].z);
            eas[e2][kb + 3] = rflf(nea[q].w);
        }

        // ---- issue x gathers now; first use after the full MLP (covered) ----
        float4 xa[4][2];
#pragma unroll
        for (int e2 = 0; e2 < 4; ++e2) {
            const float4* p = (const float4*)(x + (size_t)s[e2] * 32 + ib);
            xa[e2][0] = p[0];
            xa[e2][1] = p[1];
        }

        // ---- MLP: k=0 chunk fused with bias init ----
        v2f wk[8], acc[4][8];
        {
            v2f bia[8];
#pragma unroll
            for (int ii = 0; ii < 8; ++ii) bia[ii] = wlds[vbase + (256 + ii) * 17];
#pragma unroll
            for (int ii = 0; ii < 8; ++ii) wk[ii] = wlds[vbase + ii * 17];
#pragma unroll
            for (int e2 = 0; e2 < 4; ++e2)
#pragma unroll
                for (int ii = 0; ii < 8; ++ii)
                    acc[e2][ii] = fma2(sp2(eas[e2][0]), wk[ii], bia[ii]);
        }
#pragma unroll
        for (int k = 1; k < 8; ++k) {
#pragma unroll
            for (int ii = 0; ii < 8; ++ii)
                wk[ii] = wlds[vbase + (k * 32 + ii) * 17];
#pragma unroll
            for (int e2 = 0; e2 < 4; ++e2)
#pragma unroll
                for (int ii = 0; ii < 8; ++ii)
                    acc[e2][ii] = fma2(sp2(eas[e2][k]), wk[ii], acc[e2][ii]);
        }
#pragma unroll
        for (int e2 = 0; e2 < 4; ++e2)
#pragma unroll
            for (int ii = 0; ii < 8; ++ii)
                acc[e2][ii] = max2(acc[e2][ii], sp2(0.f));

        // ---- prefetch next batch's meta (consumed at next loop top) ----
        const int bn = b + nwv;
        const int bc = (bn < NBATCH) ? bn : b;
        nsrc = *(const int4*)(ei + 4 * bc);
        ndst = *(const int4*)(ei + N_EDGES + 4 * bc);
        {
            const float4* p = (const float4*)(ea + (size_t)bc * 32);
#pragma unroll
            for (int q = 0; q < 8; ++q) nea[q] = p[q];
        }

        // ---- msg accumulation + reduce + atomic, per edge ----
#pragma unroll
        for (int e2 = 0; e2 < 4; ++e2) {
            v2f m = acc[e2][0] * sp2(xa[e2][0].x);
            m = fma2(sp2(xa[e2][0].y), acc[e2][1], m);
            m = fma2(sp2(xa[e2][0].z), acc[e2][2], m);
            m = fma2(sp2(xa[e2][0].w), acc[e2][3], m);
            m = fma2(sp2(xa[e2][1].x), acc[e2][4], m);
            m = fma2(sp2(xa[e2][1].y), acc[e2][5], m);
            m = fma2(sp2(xa[e2][1].z), acc[e2][6], m);
            m = fma2(sp2(xa[e2][1].w), acc[e2][7], m);

            float mx = m.x, my = m.y;
            mx += __shfl_xor(mx, 16); my += __shfl_xor(my, 16);
            mx += __shfl_xor(mx, 32); my += __shfl_xor(my, 32);
            // transpose: lane l<32 takes o=l from pair holder lane l>>1
            const float vx = __shfl(mx, lane >> 1);
            const float vy = __shfl(my, lane >> 1);
            const float mv = (lane & 1) ? vy : vx;
            if (lane < 32)
                unsafeAtomicAdd(&agg[(size_t)d[e2] * 32 + lane], mv);
        }

        if (bn >= NBATCH) break;
        b = bn;
    }
}

// ---------------------------------------------------------------------------
// Finalize: one THREAD per node. h = agg+x@root+bias -> LN -> relu -> lin.
// All weights LDS-broadcast (uniform address reads = conflict-free).
// No cross-lane ops at all.
// ---------------------------------------------------------------------------
__global__ __launch_bounds__(256) void finalize_kernel(
    const float* __restrict__ agg, const float* __restrict__ x,
    const float* __restrict__ root, const float* __restrict__ bias,
    const float* __restrict__ norm_w, const float* __restrict__ norm_b,
    const float* __restrict__ lin_w, const float* __restrict__ lin_b,
    float* __restrict__ out)
{
    __shared__ v2f rlds[512];            // root  [32 i][16 oo]
    __shared__ v2f llds[256];            // lin_w [32 o][8 jj]
    __shared__ v2f blds[16], nwl[16], nbl[16], lbl[8];

    const int t = threadIdx.x;
    for (int f = t; f < 1024; f += 256) ((float*)rlds)[f] = root[f];
    for (int f = t; f < 512;  f += 256) ((float*)llds)[f] = lin_w[f];
    if (t < 32) {
        ((float*)blds)[t] = bias[t];
        ((float*)nwl)[t]  = norm_w[t];
        ((float*)nbl)[t]  = norm_b[t];
    }
    if (t < 16) ((float*)lbl)[t] = lin_b[t];
    __syncthreads();

    const int n = blockIdx.x * 256 + t;
    if (n >= N_NODES) return;

    float4 xf[8], af[8];
    {
        const float4* xp = (const float4*)(x + (size_t)n * 32);
        const float4* ap = (const float4*)(agg + (size_t)n * 32);
#pragma unroll
        for (int q = 0; q < 8; ++q) { xf[q] = xp[q]; af[q] = ap[q]; }
    }

    v2f h[16];
#pragma unroll
    for (int oo = 0; oo < 16; ++oo) {
        v2f a; a.x = ((const float*)af)[2 * oo]; a.y = ((const float*)af)[2 * oo + 1];
        h[oo] = a + blds[oo];
    }
#pragma unroll
    for (int i = 0; i < 32; ++i) {
        const float xi = ((const float*)xf)[i];
#pragma unroll
        for (int oo = 0; oo < 16; ++oo)
            h[oo] = fma2(sp2(xi), rlds[i * 16 + oo], h[oo]);
    }

    // LayerNorm over 32 features (all in this thread's registers)
    v2f sv = h[0];
#pragma unroll
    for (int oo = 1; oo < 16; ++oo) sv += h[oo];
    const float mu = (sv.x + sv.y) * (1.f / 32.f);
    const v2f mu2 = sp2(mu);
    v2f qv = (h[0] - mu2) * (h[0] - mu2);
#pragma unroll
    for (int oo = 1; oo < 16; ++oo) {
        const v2f dd = h[oo] - mu2;
        qv = fma2(dd, dd, qv);
    }
    const float var = (qv.x + qv.y) * (1.f / 32.f);
    const float rs = rsqrtf(var + 1e-5f);

    v2f r[16];
#pragma unroll
    for (int oo = 0; oo < 16; ++oo) {
        const v2f nv = fma2((h[oo] - mu2) * sp2(rs), nwl[oo], nbl[oo]);
        r[oo] = max2(nv, sp2(0.f));
    }

    // Linear 32 -> 16
    v2f a2[8];
#pragma unroll
    for (int jj = 0; jj < 8; ++jj) a2[jj] = lbl[jj];
#pragma unroll
    for (int o = 0; o < 32; ++o) {
        const float rv = (o & 1) ? r[o >> 1].y : r[o >> 1].x;
#pragma unroll
        for (int jj = 0; jj < 8; ++jj)
            a2[jj] = fma2(sp2(rv), llds[o * 8 + jj], a2[jj]);
    }

    float4* op = (float4*)(out + (size_t)n * 16);
#pragma unroll
    for (int q = 0; q < 4; ++q) {
        float4 v;
        v.x = a2[2 * q].x; v.y = a2[2 * q].y;
        v.z = a2[2 * q + 1].x; v.w = a2[2 * q + 1].y;
        op[q] = v;
    }
}

// ---------------------------------------------------------------------------
extern "C" void kernel_launch(void* const* d_in, const int* in_sizes, int n_in,
                              void* d_out, int out_size, void* d_ws, size_t ws_size,
                              hipStream_t stream)
{
    const float* x      = (const float*)d_in[0];
    const int*   ei     = (const int*)  d_in[1];
    const float* ea     = (const float*)d_in[2];
    const float* nn_w   = (const float*)d_in[3];
    const float* nn_b   = (const float*)d_in[4];
    const float* root   = (const float*)d_in[5];
    const float* bias   = (const float*)d_in[6];
    const float* norm_w = (const float*)d_in[7];
    const float* norm_b = (const float*)d_in[8];
    const float* lin_w  = (const float*)d_in[9];
    const float* lin_b  = (const float*)d_in[10];
    float* out = (float*)d_out;

    float* agg = (float*)d_ws;   // N_NODES * 32 floats = 6.4 MB

    hipMemsetAsync(agg, 0, (size_t)N_NODES * 32 * sizeof(float), stream);
    edge_kernel<<<1024, 256, 0, stream>>>(x, ei, ea, nn_w, nn_b, agg);
    finalize_kernel<<<(N_NODES + 255) / 256, 256, 0, stream>>>(
        agg, x, root, bias, norm_w, norm_b, lin_w, lin_b, out);
}

// Round 7
// 142.132 us; speedup vs baseline: 1.6074x; 1.6074x over previous
//
#include <hip/hip_runtime.h>
#include <hip/hip_bf16.h>

#define N_NODES 50000
#define N_EDGES 200000
#define NTILES  (N_EDGES / 32)      // 6250 tiles of 32 edges
#define EBLK    768                 // 3 blocks/CU (LDS-limited)
#define TWAVES  (EBLK * 4)          // 3072 persistent waves

typedef float  v2f    __attribute__((ext_vector_type(2)));
typedef float  f32x16 __attribute__((ext_vector_type(16)));
typedef short  s16x8  __attribute__((ext_vector_type(8)));

static __device__ inline v2f sp2(float s) { v2f r; r.x = s; r.y = s; return r; }

static __device__ inline v2f fma2(v2f a, v2f b, v2f c) {
#if __has_builtin(__builtin_elementwise_fma)
    return __builtin_elementwise_fma(a, b, c);
#else
    v2f r; r.x = fmaf(a.x, b.x, c.x); r.y = fmaf(a.y, b.y, c.y); return r;
#endif
}

static __device__ inline v2f max2(v2f a, v2f b) {
#if __has_builtin(__builtin_elementwise_max)
    return __builtin_elementwise_max(a, b);
#else
    v2f r; r.x = fmaxf(a.x, b.x); r.y = fmaxf(a.y, b.y); return r;
#endif
}

static __device__ inline unsigned short bf_rne(float f) {
    unsigned int u = __float_as_uint(f);
    u += 0x7fffu + ((u >> 16) & 1u);
    return (unsigned short)(u >> 16);
}

// ---------------------------------------------------------------------------
// Edge kernel (MFMA). Per 32-edge tile, per i (0..31):
//   D[o][e] = mfma_32x32x16_bf16(A, B):  A[o][k] = [w[k][i*32+o] x8 | w x7, bias]
//                                        B[k][e] = [ea_hi[e][k] x8 | ea_lo x7, 1]
//   msg[e][o] += x[src[e]][i] * relu(D[o][e])   (packed fp32 VALU)
// Lane = (e or o) = lane&31; hsel = lane>>5 picks K-half / row offset.
// msg transposed through per-wave LDS -> 32-lane contiguous atomics.
// ---------------------------------------------------------------------------
__global__ __launch_bounds__(256, 3) void edge_kernel(
    const float* __restrict__ x, const int* __restrict__ ei,
    const float* __restrict__ ea, const float* __restrict__ nn_w,
    const float* __restrict__ nn_b, float* __restrict__ agg)
{
    __shared__ unsigned short wT[1024 * 16];   // 32 KB: [col=i*32+o][16 bf16]
    __shared__ float tl4[4][32 * 33];          // 16.9 KB: per-wave msg transpose

    // ---- prologue: weights -> bf16, K-layout [w0..w7 | w0..w6, bias] ----
    for (int c = threadIdx.x; c < 1024; c += 256) {
        unsigned short row[16];
#pragma unroll
        for (int k = 0; k < 8; ++k) row[k] = bf_rne(nn_w[k * 1024 + c]);
#pragma unroll
        for (int k = 0; k < 7; ++k) row[8 + k] = row[k];
        row[15] = bf_rne(nn_b[c]);
        unsigned int w[8];
#pragma unroll
        for (int q = 0; q < 8; ++q)
            w[q] = (unsigned int)row[2 * q] | ((unsigned int)row[2 * q + 1] << 16);
        uint4* p = (uint4*)(wT + c * 16);
        uint4 lo_; lo_.x = w[0]; lo_.y = w[1]; lo_.z = w[2]; lo_.w = w[3];
        uint4 hi_; hi_.x = w[4]; hi_.y = w[5]; hi_.z = w[6]; hi_.w = w[7];
        p[0] = lo_; p[1] = hi_;
    }
    __syncthreads();

    const int lane = threadIdx.x & 63;
    const int eo   = lane & 31;          // edge slot (compute) / o (atomic phase)
    const int hsel = lane >> 5;
    float* tl = tl4[threadIdx.x >> 6];

    int t = (int)((blockIdx.x * 256u + threadIdx.x) >> 6);   // wave id = first tile
    if (t >= NTILES) return;

    // meta for tile t
    int    sc  = ei[t * 32 + eo];
    int    dc  = ei[N_EDGES + t * 32 + eo];
    float4 ea0 = ((const float4*)(ea + (size_t)(t * 32 + eo) * 8))[0];
    float4 ea1 = ((const float4*)(ea + (size_t)(t * 32 + eo) * 8))[1];

    // x rows for tile t (per-lane gather, 32 floats)
    float4 xq[8];
    {
        const float4* xp = (const float4*)(x + (size_t)sc * 32);
#pragma unroll
        for (int q = 0; q < 8; ++q) xq[q] = xp[q];
    }

    // meta for tile t+TWAVES (clamped)
    int tn = t + TWAVES;
    int tc = tn < NTILES ? tn : t;
    int    sn  = ei[tc * 32 + eo];
    int    dn  = ei[N_EDGES + tc * 32 + eo];
    float4 na0 = ((const float4*)(ea + (size_t)(tc * 32 + eo) * 8))[0];
    float4 na1 = ((const float4*)(ea + (size_t)(tc * 32 + eo) * 8))[1];

    const f32x16 zf = {0.f,0.f,0.f,0.f,0.f,0.f,0.f,0.f,
                       0.f,0.f,0.f,0.f,0.f,0.f,0.f,0.f};

    while (true) {
        // ---- B fragment: [ea_hi(8) | ea_lo(7), 1.0] ----
        const float ef[8] = {ea0.x, ea0.y, ea0.z, ea0.w,
                             ea1.x, ea1.y, ea1.z, ea1.w};
        s16x8 bfrag;
#pragma unroll
        for (int j = 0; j < 8; ++j) {
            const float f = ef[j];
            const unsigned short hi = bf_rne(f);
            unsigned short v;
            if (j < 7) {
                const unsigned short lo =
                    bf_rne(f - __uint_as_float(((unsigned int)hi) << 16));
                v = hsel ? lo : hi;
            } else {
                v = hsel ? (unsigned short)0x3F80 : hi;
            }
            bfrag[j] = (short)v;
        }

        const float4* xpn = (const float4*)(x + (size_t)sn * 32);

        v2f m2[8];
#pragma unroll
        for (int p = 0; p < 8; ++p) m2[p] = sp2(0.f);

        // ---- main loop: 32 MFMAs + packed relu/msg; x(t+1) prefetch fused ----
#pragma unroll
        for (int i = 0; i < 32; ++i) {
            const s16x8 a = *(const s16x8*)(wT + (i * 32 + eo) * 16 + hsel * 8);
            const f32x16 d =
                __builtin_amdgcn_mfma_f32_32x32x16_bf16(a, bfrag, zf, 0, 0, 0);
            const float4 xc = xq[i >> 2];
            const float xv = (i & 3) == 0 ? xc.x : (i & 3) == 1 ? xc.y
                           : (i & 3) == 2 ? xc.z : xc.w;
            const v2f x2 = sp2(xv);
#pragma unroll
            for (int p = 0; p < 8; ++p) {
                v2f dd; dd.x = d[2 * p]; dd.y = d[2 * p + 1];
                m2[p] = fma2(x2, max2(dd, sp2(0.f)), m2[p]);
            }
            if ((i & 3) == 3) xq[i >> 2] = xpn[i >> 2];   // prefetch next tile
        }

        // ---- transpose msg through LDS: tl[o][e] ----
#pragma unroll
        for (int p = 0; p < 8; ++p) {
            const int r0 = 2 * p, r1 = 2 * p + 1;
            const int o0 = (r0 & 3) + 8 * (r0 >> 2) + 4 * hsel;
            const int o1 = (r1 & 3) + 8 * (r1 >> 2) + 4 * hsel;
            tl[o0 * 33 + eo] = m2[p].x;
            tl[o1 * 33 + eo] = m2[p].y;
        }

        // ---- contiguous atomics: 2 edges per round, 32 lanes each ----
#pragma unroll
        for (int r = 0; r < 16; ++r) {
            const int d0 = __builtin_amdgcn_readlane(dc, 2 * r);
            const int d1 = __builtin_amdgcn_readlane(dc, 2 * r + 1);
            const int dr = hsel ? d1 : d0;
            const float v = tl[eo * 33 + 2 * r + hsel];
            unsafeAtomicAdd(&agg[(size_t)dr * 32 + eo], v);
        }

        if (tn >= NTILES) break;
        t = tn; sc = sn; dc = dn; ea0 = na0; ea1 = na1;
        tn = t + TWAVES; tc = tn < NTILES ? tn : t;
        sn  = ei[tc * 32 + eo];
        dn  = ei[N_EDGES + tc * 32 + eo];
        na0 = ((const float4*)(ea + (size_t)(tc * 32 + eo) * 8))[0];
        na1 = ((const float4*)(ea + (size_t)(tc * 32 + eo) * 8))[1];
    }
}

// ---------------------------------------------------------------------------
// Finalize: one THREAD per node. h = agg+x@root+bias -> LN -> relu -> lin.
// All weights LDS-broadcast; no cross-lane ops.
// ---------------------------------------------------------------------------
__global__ __launch_bounds__(256) void finalize_kernel(
    const float* __restrict__ agg, const float* __restrict__ x,
    const float* __restrict__ root, const float* __restrict__ bias,
    const float* __restrict__ norm_w, const float* __restrict__ norm_b,
    const float* __restrict__ lin_w, const float* __restrict__ lin_b,
    float* __restrict__ out)
{
    __shared__ v2f rlds[512];            // root  [32 i][16 oo]
    __shared__ v2f llds[256];            // lin_w [32 o][8 jj]
    __shared__ v2f blds[16], nwl[16], nbl[16], lbl[8];

    const int t = threadIdx.x;
    for (int f = t; f < 1024; f += 256) ((float*)rlds)[f] = root[f];
    for (int f = t; f < 512;  f += 256) ((float*)llds)[f] = lin_w[f];
    if (t < 32) {
        ((float*)blds)[t] = bias[t];
        ((float*)nwl)[t]  = norm_w[t];
        ((float*)nbl)[t]  = norm_b[t];
    }
    if (t < 16) ((float*)lbl)[t] = lin_b[t];
    __syncthreads();

    const int n = blockIdx.x * 256 + t;
    if (n >= N_NODES) return;

    float4 xf[8], af[8];
    {
        const float4* xp = (const float4*)(x + (size_t)n * 32);
        const float4* ap = (const float4*)(agg + (size_t)n * 32);
#pragma unroll
        for (int q = 0; q < 8; ++q) { xf[q] = xp[q]; af[q] = ap[q]; }
    }

    v2f h[16];
#pragma unroll
    for (int oo = 0; oo < 16; ++oo) {
        v2f a; a.x = ((const float*)af)[2 * oo]; a.y = ((const float*)af)[2 * oo + 1];
        h[oo] = a + blds[oo];
    }
#pragma unroll
    for (int i = 0; i < 32; ++i) {
        const float xi = ((const float*)xf)[i];
#pragma unroll
        for (int oo = 0; oo < 16; ++oo)
            h[oo] = fma2(sp2(xi), rlds[i * 16 + oo], h[oo]);
    }

    v2f sv = h[0];
#pragma unroll
    for (int oo = 1; oo < 16; ++oo) sv += h[oo];
    const float mu = (sv.x + sv.y) * (1.f / 32.f);
    const v2f mu2 = sp2(mu);
    v2f qv = (h[0] - mu2) * (h[0] - mu2);
#pragma unroll
    for (int oo = 1; oo < 16; ++oo) {
        const v2f dd = h[oo] - mu2;
        qv = fma2(dd, dd, qv);
    }
    const float var = (qv.x + qv.y) * (1.f / 32.f);
    const float rs = rsqrtf(var + 1e-5f);

    v2f r[16];
#pragma unroll
    for (int oo = 0; oo < 16; ++oo) {
        const v2f nv = fma2((h[oo] - mu2) * sp2(rs), nwl[oo], nbl[oo]);
        r[oo] = max2(nv, sp2(0.f));
    }

    v2f a2[8];
#pragma unroll
    for (int jj = 0; jj < 8; ++jj) a2[jj] = lbl[jj];
#pragma unroll
    for (int o = 0; o < 32; ++o) {
        const float rv = (o & 1) ? r[o >> 1].y : r[o >> 1].x;
#pragma unroll
        for (int jj = 0; jj < 8; ++jj)
            a2[jj] = fma2(sp2(rv), llds[o * 8 + jj], a2[jj]);
    }

    float4* op = (float4*)(out + (size_t)n * 16);
#pragma unroll
    for (int q = 0; q < 4; ++q) {
        float4 v;
        v.x = a2[2 * q].x; v.y = a2[2 * q].y;
        v.z = a2[2 * q + 1].x; v.w = a2[2 * q + 1].y;
        op[q] = v;
    }
}

// ---------------------------------------------------------------------------
extern "C" void kernel_launch(void* const* d_in, const int* in_sizes, int n_in,
                              void* d_out, int out_size, void* d_ws, size_t ws_size,
                              hipStream_t stream)
{
    const float* x      = (const float*)d_in[0];
    const int*   ei     = (const int*)  d_in[1];
    const float* ea     = (const float*)d_in[2];
    const float* nn_w   = (const float*)d_in[3];
    const float* nn_b   = (const float*)d_in[4];
    const float* root   = (const float*)d_in[5];
    const float* bias   = (const float*)d_in[6];
    const float* norm_w = (const float*)d_in[7];
    const float* norm_b = (const float*)d_in[8];
    const float* lin_w  = (const float*)d_in[9];
    const float* lin_b  = (const float*)d_in[10];
    float* out = (float*)d_out;

    float* agg = (float*)d_ws;   // N_NODES * 32 floats = 6.4 MB

    hipMemsetAsync(agg, 0, (size_t)N_NODES * 32 * sizeof(float), stream);
    edge_kernel<<<EBLK, 256, 0, stream>>>(x, ei, ea, nn_w, nn_b, agg);
    finalize_kernel<<<(N_NODES + 255) / 256, 256, 0, stream>>>(
        agg, x, root, bias, norm_w, norm_b, lin_w, lin_b, out);
}